// Round 1
// baseline (494.859 us; speedup 1.0000x reference)
//
#include <hip/hip_runtime.h>
#include <stdint.h>

// Problem constants
#define BB 32
#define FO 520          // F*O
#define M1 16640        // BB*FO
#define K1 2048         // IN
#define N1 1024         // 2*G (concatenated rel|tem)
#define GG 512          // G
#define K2 544          // 520 padded to mult of 32
#define M2 640          // 520 padded to mult of 128

typedef unsigned short u16;
typedef short v8s __attribute__((ext_vector_type(8)));   // 8 bf16 (4 VGPRs) MFMA A/B frag
typedef float v4f __attribute__((ext_vector_type(4)));   // MFMA C/D frag

__device__ __forceinline__ u16 f2bf(float f) {
  union { float f; unsigned u; } v; v.f = f;
  unsigned r = v.u + 0x7fffu + ((v.u >> 16) & 1u);   // RNE, inputs finite
  return (u16)(r >> 16);
}

__device__ __forceinline__ float fast_tanh(float x) {
  float cx = fminf(fmaxf(x, -15.f), 15.f);
  float e = __expf(2.f * cx);
  return (e - 1.f) / (e + 1.f);
}

// ---------- cast region_feats fp32 -> bf16, 8 elems/thread ----------
__global__ void cast8_kernel(const float* __restrict__ in, u16* __restrict__ o, int n8) {
  int i = blockIdx.x * blockDim.x + threadIdx.x;
  if (i >= n8) return;
  const float4* p = (const float4*)in;
  float4 a = p[2 * i], b = p[2 * i + 1];
  v8s v;
  v[0] = (short)f2bf(a.x); v[1] = (short)f2bf(a.y);
  v[2] = (short)f2bf(a.z); v[3] = (short)f2bf(a.w);
  v[4] = (short)f2bf(b.x); v[5] = (short)f2bf(b.y);
  v[6] = (short)f2bf(b.z); v[7] = (short)f2bf(b.w);
  *(v8s*)(o + (size_t)i * 8) = v;
}

// ---------- pack rel_W | tem_W -> Wc [1024][2048] bf16 (B^T layout) ----------
__global__ void castw_kernel(const float* __restrict__ relW, const float* __restrict__ temW,
                             u16* __restrict__ o) {
  int i = blockIdx.x * 256 + threadIdx.x;      // 262144 chunks of 8
  size_t off = (size_t)i * 8;
  const size_t half = (size_t)GG * K1;
  const float* src = (off < half) ? (relW + off) : (temW + (off - half));
  float4 a = *(const float4*)src, b = *(const float4*)(src + 4);
  v8s v;
  v[0] = (short)f2bf(a.x); v[1] = (short)f2bf(a.y);
  v[2] = (short)f2bf(a.z); v[3] = (short)f2bf(a.w);
  v[4] = (short)f2bf(b.x); v[5] = (short)f2bf(b.y);
  v[6] = (short)f2bf(b.z); v[7] = (short)f2bf(b.w);
  *(v8s*)(o + off) = v;
}

// ---------- R[m,g] = (sum_j mask*emb[idx_j]) / msum ; one row per block ----------
__global__ void emb_kernel(const int* __restrict__ rel, const float* __restrict__ emb,
                           float* __restrict__ R) {
  const int m = blockIdx.x;                    // 16640
  const int g = threadIdx.x * 4;               // 128 threads * float4 = 512
  const int* rp = rel + (size_t)m * 20;
  float s0 = 0.f, s1 = 0.f, s2 = 0.f, s3 = 0.f, cnt = 0.f;
#pragma unroll
  for (int j = 0; j < 20; ++j) {
    int idx = rp[j];                           // uniform across block -> scalar branch
    if (idx > 0) {
      cnt += 1.f;
      const float4 e = *(const float4*)(emb + (size_t)idx * GG + g);
      s0 += e.x; s1 += e.y; s2 += e.z; s3 += e.w;
    }
  }
  float rs = 1.f / cnt;                        // msum>0 for this data
  float4 o = { s0 * rs, s1 * rs, s2 * rs, s3 * rs };
  *(float4*)(R + (size_t)m * GG + g) = o;
}

// ---------- tem_feats fp32 -> A2 [32][640][544] bf16 (zero-padded) + row sums ----------
__global__ void casta2_kernel(const float* __restrict__ tem, u16* __restrict__ A2,
                              float* __restrict__ tsum) {
  const int blk = blockIdx.x;                  // 32*640
  const int b = blk / M2;
  const int i = blk % M2;
  const int lane = threadIdx.x;                // 64
  u16* orow = A2 + ((size_t)b * M2 + i) * K2;
  if (i >= FO) {
    for (int j = lane; j < K2; j += 64) orow[j] = 0;
    return;
  }
  const float* srow = tem + ((size_t)b * FO + i) * FO;
  float s = 0.f;
  for (int j = lane; j < K2; j += 64) {
    float v = (j < FO) ? srow[j] : 0.f;
    s += v;
    orow[j] = f2bf(v);
  }
#pragma unroll
  for (int off = 32; off > 0; off >>= 1) s += __shfl_down(s, off);
  if (lane == 0) tsum[(size_t)b * FO + i] = s;
}

// ---------- transpose tem_nat [16640][512] -> BT [32][512][544] (B^T for GEMM2) ----------
__global__ void transp_kernel(const u16* __restrict__ in, u16* __restrict__ o) {
  __shared__ u16 tile[32][33];
  const int jb = blockIdx.x, gb = blockIdx.y, b = blockIdx.z;
  const int tx = threadIdx.x, ty = threadIdx.y;   // 32, 8
#pragma unroll
  for (int i = 0; i < 4; ++i) {
    int j = jb * 32 + ty + i * 8;
    tile[ty + i * 8][tx] = (j < FO) ? in[((size_t)b * FO + j) * GG + gb * 32 + tx] : (u16)0;
  }
  __syncthreads();
#pragma unroll
  for (int i = 0; i < 4; ++i) {
    int g = gb * 32 + ty + i * 8;
    int j = jb * 32 + tx;
    o[((size_t)b * GG + g) * K2 + j] = tile[tx][ty + i * 8];
  }
}

// ---------- GEMM1: [16640x2048]x[2048x1024] bf16 MFMA, fused epilogues ----------
__global__ __launch_bounds__(256) void gemm1_kernel(
    const u16* __restrict__ A, const u16* __restrict__ Wc,
    const float* __restrict__ R,
    const float* __restrict__ rel_b, const float* __restrict__ tem_b,
    const float* __restrict__ bn_w, const float* __restrict__ bn_b,
    const float* __restrict__ bn_rm, const float* __restrict__ bn_rv,
    float* __restrict__ out, u16* __restrict__ tem_nat) {
  __shared__ u16 As[128 * 32];
  __shared__ u16 Bs[128 * 32];
  const int tid = threadIdx.x;
  const int lane = tid & 63;
  const int wv = tid >> 6, wm = wv >> 1, wn = wv & 1;   // 2x2 waves of 64x64
  const int m0 = blockIdx.x * 128;
  const int n0 = blockIdx.y * 128;
  const int quad = lane >> 4, r16 = lane & 15;

  v4f acc[4][4];
#pragma unroll
  for (int i = 0; i < 4; ++i)
#pragma unroll
    for (int j = 0; j < 4; ++j) { v4f z = {0.f, 0.f, 0.f, 0.f}; acc[i][j] = z; }

  for (int k0 = 0; k0 < K1; k0 += 32) {
    __syncthreads();
#pragma unroll
    for (int i = 0; i < 2; ++i) {
      const int L = i * 256 + tid;          // chunk id: 512 chunks of 16B per tile
      const int r = L >> 2, c = L & 3;
      const u16* ga = A + (size_t)(m0 + r) * K1 + k0 + c * 8;
      const u16* gb = Wc + (size_t)(n0 + r) * K1 + k0 + c * 8;
      u16* la = &As[(size_t)(i * 256 + wv * 64) * 8];   // wave-uniform base + lane*16
      u16* lb = &Bs[(size_t)(i * 256 + wv * 64) * 8];
      __builtin_amdgcn_global_load_lds((const __attribute__((address_space(1))) void*)ga,
                                       (__attribute__((address_space(3))) void*)la, 16, 0, 0);
      __builtin_amdgcn_global_load_lds((const __attribute__((address_space(1))) void*)gb,
                                       (__attribute__((address_space(3))) void*)lb, 16, 0, 0);
    }
    __syncthreads();
    v8s af[4], bf[4];
#pragma unroll
    for (int t = 0; t < 4; ++t) {
      af[t] = *(const v8s*)&As[(wm * 64 + t * 16 + r16) * 32 + quad * 8];
      bf[t] = *(const v8s*)&Bs[(wn * 64 + t * 16 + r16) * 32 + quad * 8];
    }
#pragma unroll
    for (int mt = 0; mt < 4; ++mt)
#pragma unroll
      for (int nt = 0; nt < 4; ++nt)
        acc[mt][nt] = __builtin_amdgcn_mfma_f32_16x16x32_bf16(af[mt], bf[nt], acc[mt][nt], 0, 0, 0);
  }

  const bool relhalf = (n0 < GG);   // block-uniform
#pragma unroll
  for (int mt = 0; mt < 4; ++mt) {
#pragma unroll
    for (int nt = 0; nt < 4; ++nt) {
      const int n = n0 + wn * 64 + nt * 16 + r16;          // C/D col = lane&15
      const int mbase = m0 + wm * 64 + mt * 16 + quad * 4; // C/D row = quad*4+reg
#pragma unroll
      for (int r = 0; r < 4; ++r) {
        const int m = mbase + r;
        float v = acc[mt][nt][r];
        if (relhalf) {
          v += rel_b[n] + R[(size_t)m * GG + n];
          const int fo = m % FO;
          float inv = bn_w[fo] * rsqrtf(bn_rv[fo] + 1e-5f);
          out[(size_t)m * N1 + n] = (fast_tanh(v) - bn_rm[fo]) * inv + bn_b[fo];
        } else {
          v += tem_b[n - GG];
          tem_nat[(size_t)m * GG + (n - GG)] = f2bf(v);
        }
      }
    }
  }
}

// ---------- GEMM2: batched [640x544]x[544x512], fused /tem_sum + tanh + BN ----------
__global__ __launch_bounds__(256) void gemm2_kernel(
    const u16* __restrict__ A2, const u16* __restrict__ BT,
    const float* __restrict__ tsum,
    const float* __restrict__ bn_w, const float* __restrict__ bn_b,
    const float* __restrict__ bn_rm, const float* __restrict__ bn_rv,
    float* __restrict__ out) {
  __shared__ u16 As[128 * 32];
  __shared__ u16 Bs[128 * 32];
  const int tid = threadIdx.x;
  const int lane = tid & 63;
  const int wv = tid >> 6, wm = wv >> 1, wn = wv & 1;
  const int m0 = blockIdx.x * 128;       // 5 tiles over 640
  const int n0 = blockIdx.y * 128;       // 4 tiles over 512
  const int b = blockIdx.z;
  const u16* Ab = A2 + (size_t)b * M2 * K2;
  const u16* Bb = BT + (size_t)b * GG * K2;
  const int quad = lane >> 4, r16 = lane & 15;

  v4f acc[4][4];
#pragma unroll
  for (int i = 0; i < 4; ++i)
#pragma unroll
    for (int j = 0; j < 4; ++j) { v4f z = {0.f, 0.f, 0.f, 0.f}; acc[i][j] = z; }

  for (int k0 = 0; k0 < K2; k0 += 32) {
    __syncthreads();
#pragma unroll
    for (int i = 0; i < 2; ++i) {
      const int L = i * 256 + tid;
      const int r = L >> 2, c = L & 3;
      const u16* ga = Ab + (size_t)(m0 + r) * K2 + k0 + c * 8;
      const u16* gb = Bb + (size_t)(n0 + r) * K2 + k0 + c * 8;
      u16* la = &As[(size_t)(i * 256 + wv * 64) * 8];
      u16* lb = &Bs[(size_t)(i * 256 + wv * 64) * 8];
      __builtin_amdgcn_global_load_lds((const __attribute__((address_space(1))) void*)ga,
                                       (__attribute__((address_space(3))) void*)la, 16, 0, 0);
      __builtin_amdgcn_global_load_lds((const __attribute__((address_space(1))) void*)gb,
                                       (__attribute__((address_space(3))) void*)lb, 16, 0, 0);
    }
    __syncthreads();
    v8s af[4], bf[4];
#pragma unroll
    for (int t = 0; t < 4; ++t) {
      af[t] = *(const v8s*)&As[(wm * 64 + t * 16 + r16) * 32 + quad * 8];
      bf[t] = *(const v8s*)&Bs[(wn * 64 + t * 16 + r16) * 32 + quad * 8];
    }
#pragma unroll
    for (int mt = 0; mt < 4; ++mt)
#pragma unroll
      for (int nt = 0; nt < 4; ++nt)
        acc[mt][nt] = __builtin_amdgcn_mfma_f32_16x16x32_bf16(af[mt], bf[nt], acc[mt][nt], 0, 0, 0);
  }

#pragma unroll
  for (int mt = 0; mt < 4; ++mt) {
#pragma unroll
    for (int nt = 0; nt < 4; ++nt) {
      const int g = n0 + wn * 64 + nt * 16 + r16;
      const int ibase = m0 + wm * 64 + mt * 16 + quad * 4;
#pragma unroll
      for (int r = 0; r < 4; ++r) {
        const int i = ibase + r;
        if (i < FO) {
          float v = acc[mt][nt][r] / tsum[(size_t)b * FO + i];
          float inv = bn_w[i] * rsqrtf(bn_rv[i] + 1e-5f);
          out[((size_t)(b * FO + i)) * N1 + GG + g] =
              (fast_tanh(v) - bn_rm[i]) * inv + bn_b[i];
        }
      }
    }
  }
}

extern "C" void kernel_launch(void* const* d_in, const int* in_sizes, int n_in,
                              void* d_out, int out_size, void* d_ws, size_t ws_size,
                              hipStream_t stream) {
  const float* region_feats = (const float*)d_in[0];
  // d_in[1] region_masks: unused by reference
  const int* rel_feats = (const int*)d_in[2];
  const float* tem_feats = (const float*)d_in[3];
  const float* rel_W = (const float*)d_in[4];
  const float* rel_b = (const float*)d_in[5];
  const float* rel_emb = (const float*)d_in[6];
  const float* tem_W = (const float*)d_in[7];
  const float* tem_b = (const float*)d_in[8];
  const float* bn_w = (const float*)d_in[9];
  const float* bn_b = (const float*)d_in[10];
  const float* bn_rm = (const float*)d_in[11];
  const float* bn_rv = (const float*)d_in[12];
  float* out = (float*)d_out;

  // Workspace layout (with liveness aliasing): total 123.5 MB
  char* base = (char*)d_ws;
  u16* A1 = (u16*)base;                                   // [16640][2048] bf16 : 68,157,440
  u16* BT = (u16*)base;                                   // aliases A1 (dead after GEMM1)
  u16* Wc = (u16*)(base + 68157440);                      // [1024][2048] bf16 : 4,194,304
  float* R = (float*)(base + 72351744);                   // [16640][512] f32  : 34,078,720
  u16* A2 = (u16*)(base + 72351744);                      // aliases R (dead after GEMM1)
  u16* tem_nat = (u16*)(base + 106430464);                // [16640][512] bf16 : 17,039,360
  float* tsum = (float*)(base + 123469824);               // [32*520] f32      : 66,560

  cast8_kernel<<<16640, 256, 0, stream>>>(region_feats, A1, 4259840);
  castw_kernel<<<1024, 256, 0, stream>>>(rel_W, tem_W, Wc);
  emb_kernel<<<16640, 128, 0, stream>>>(rel_feats, rel_emb, R);
  gemm1_kernel<<<dim3(130, 8), 256, 0, stream>>>(A1, Wc, R, rel_b, tem_b,
                                                 bn_w, bn_b, bn_rm, bn_rv, out, tem_nat);
  casta2_kernel<<<20480, 64, 0, stream>>>(tem_feats, A2, tsum);        // after GEMM1 (A2 over R)
  transp_kernel<<<dim3(17, 16, 32), dim3(32, 8), 0, stream>>>(tem_nat, BT);  // BT over A1
  gemm2_kernel<<<dim3(5, 4, 32), 256, 0, stream>>>(A2, BT, tsum,
                                                   bn_w, bn_b, bn_rm, bn_rv, out);
}

// Round 2
// 461.750 us; speedup vs baseline: 1.0717x; 1.0717x over previous
//
#include <hip/hip_runtime.h>
#include <stdint.h>

// Problem constants
#define BB 32
#define FO 520          // F*O
#define M1 16640        // BB*FO
#define KIN 2048        // IN
#define KA 2112         // IN + 64 (S-matrix columns folded into K)
#define N1 1024         // 2*G (concatenated rel|tem)
#define GG 512          // G
#define K2 544          // 520 padded to mult of 32
#define M2 640          // 520 padded to mult of 128

typedef unsigned short u16;
typedef short v8s __attribute__((ext_vector_type(8)));   // 8 bf16 (4 VGPRs) MFMA A/B frag
typedef float v4f __attribute__((ext_vector_type(4)));   // MFMA C/D frag

__device__ __forceinline__ u16 f2bf(float f) {
  union { float f; unsigned u; } v; v.f = f;
  unsigned r = v.u + 0x7fffu + ((v.u >> 16) & 1u);   // RNE, inputs finite
  return (u16)(r >> 16);
}

__device__ __forceinline__ float fast_tanh(float x) {
  float cx = fminf(fmaxf(x, -15.f), 15.f);
  float e = __expf(2.f * cx);
  return (e - 1.f) / (e + 1.f);
}

// ---------- cast region_feats fp32 -> bf16 row + append S[m, 0:64] ----------
// S[m,l] = count_j(rel[m,j]==l+1) / msum[m]  (l<52, else 0): emb fold as GEMM K-ext.
__global__ void cast8_kernel(const float* __restrict__ rf, const int* __restrict__ rel,
                             u16* __restrict__ A1) {
  const int m = blockIdx.x;          // 16640
  const int t = threadIdx.x;         // 256 -> exactly one row of 2048
  const float4* p = (const float4*)(rf + (size_t)m * KIN);
  u16* orow = A1 + (size_t)m * KA;
  float4 a = p[2 * t], b = p[2 * t + 1];
  v8s v;
  v[0] = (short)f2bf(a.x); v[1] = (short)f2bf(a.y);
  v[2] = (short)f2bf(a.z); v[3] = (short)f2bf(a.w);
  v[4] = (short)f2bf(b.x); v[5] = (short)f2bf(b.y);
  v[6] = (short)f2bf(b.z); v[7] = (short)f2bf(b.w);
  *(v8s*)(orow + t * 8) = v;
  if (t < 64) {                      // wave 0: build S row
    const int* rp = rel + (size_t)m * 20;
    int cnt = 0, ms = 0;
#pragma unroll
    for (int j = 0; j < 20; ++j) {   // uniform addresses -> scalar loads
      int ix = rp[j];
      cnt += (ix == t + 1);
      ms += (ix > 0);
    }
    float sval = (t < 52 && ms > 0) ? (float)cnt / (float)ms : 0.f;
    orow[KIN + t] = f2bf(sval);
  }
}

// ---------- pack rel_W|rel_emb^T and tem_W|0 -> Wc [1024][2112] bf16 (B^T) ----------
__global__ void castw_kernel(const float* __restrict__ relW, const float* __restrict__ temW,
                             const float* __restrict__ emb, u16* __restrict__ o) {
  const int n = blockIdx.x;          // 1024
  u16* orow = o + (size_t)n * KA;
  const float* src = (n < GG) ? (relW + (size_t)n * KIN) : (temW + (size_t)(n - GG) * KIN);
  for (int k = threadIdx.x; k < KIN; k += 256) orow[k] = f2bf(src[k]);
  for (int k = KIN + threadIdx.x; k < KA; k += 256) {
    int l = k - KIN;
    float v = (n < GG && l < 52) ? emb[(size_t)(l + 1) * GG + n] : 0.f;
    orow[k] = f2bf(v);
  }
}

// ---------- tem_feats fp32 -> A2 [32][640][544] bf16 (zero-padded) + row sums ----------
__global__ void casta2_kernel(const float* __restrict__ tem, u16* __restrict__ A2,
                              float* __restrict__ tsum) {
  const int w = threadIdx.x >> 6;                 // wave 0..3 -> one row each
  const int l = threadIdx.x & 63;
  const int row = blockIdx.x * 4 + w;             // 0..20479 over [32][640]
  const int b = row / M2, i = row % M2;
  u16* orow = A2 + (size_t)row * K2;
  v8s z = {0, 0, 0, 0, 0, 0, 0, 0};
  if (i >= FO) {                                  // pure pad row
    *(v8s*)(orow + l * 8) = z;
    if (l < 4) *(v8s*)(orow + (64 + l) * 8) = z;
    return;
  }
  const float* srow = tem + ((size_t)b * FO + i) * FO;   // row base 2080B: 16B-aligned
  float s = 0.f;
#pragma unroll
  for (int pass = 0; pass < 2; ++pass) {
    int c = (pass == 0) ? l : (64 + l);
    if (pass == 1 && l >= 4) break;
    if (c < 65) {                                 // 520 = 65 chunks of 8, all full
      float4 a = *(const float4*)(srow + 8 * c);
      float4 bb = *(const float4*)(srow + 8 * c + 4);
      s += a.x + a.y + a.z + a.w + bb.x + bb.y + bb.z + bb.w;
      v8s v;
      v[0] = (short)f2bf(a.x); v[1] = (short)f2bf(a.y);
      v[2] = (short)f2bf(a.z); v[3] = (short)f2bf(a.w);
      v[4] = (short)f2bf(bb.x); v[5] = (short)f2bf(bb.y);
      v[6] = (short)f2bf(bb.z); v[7] = (short)f2bf(bb.w);
      *(v8s*)(orow + c * 8) = v;
    } else {
      *(v8s*)(orow + c * 8) = z;
    }
  }
#pragma unroll
  for (int off = 32; off > 0; off >>= 1) s += __shfl_down(s, off);
  if (l == 0) tsum[(size_t)b * FO + i] = s;
}

// ---------- transpose tem_nat [16640][512] -> BT [32][512][544] ----------
__global__ void transp_kernel(const u16* __restrict__ in, u16* __restrict__ o) {
  __shared__ u16 tile[64][66];                    // stored transposed: tile[g_local][j_local]
  const int jb = blockIdx.x;                      // 9 tiles over 520->544
  const int gb = blockIdx.y;                      // 8 tiles over 512
  const int b = blockIdx.z;
  const int tx = threadIdx.x, ty = threadIdx.y;   // 32, 8
#pragma unroll
  for (int r = 0; r < 8; ++r) {
    int jl = ty + 8 * r;
    int j = jb * 64 + jl;
    unsigned v = 0;
    if (j < FO) v = *(const unsigned*)(in + ((size_t)b * FO + j) * GG + gb * 64 + 2 * tx);
    tile[2 * tx][jl] = (u16)(v & 0xffff);
    tile[2 * tx + 1][jl] = (u16)(v >> 16);
  }
  __syncthreads();
#pragma unroll
  for (int r = 0; r < 8; ++r) {
    int gl = ty + 8 * r;
    int j2 = jb * 64 + 2 * tx;
    if (j2 < K2) {
      unsigned v = *(const unsigned*)&tile[gl][2 * tx];    // 4B-aligned (66 even)
      *(unsigned*)(o + ((size_t)b * GG + gb * 64 + gl) * K2 + j2) = v;
    }
  }
}

// ---------- GEMM1: [16640x2112]x[2112x1024] bf16 MFMA, fused epilogues ----------
__global__ __launch_bounds__(256) void gemm1_kernel(
    const u16* __restrict__ A, const u16* __restrict__ Wc,
    const float* __restrict__ rel_b, const float* __restrict__ tem_b,
    const float* __restrict__ bn_w, const float* __restrict__ bn_b,
    const float* __restrict__ bn_rm, const float* __restrict__ bn_rv,
    float* __restrict__ out, u16* __restrict__ tem_nat) {
  __shared__ u16 As[128 * 32];
  __shared__ u16 Bs[128 * 32];
  const int tid = threadIdx.x;
  const int lane = tid & 63;
  const int wv = tid >> 6, wm = wv >> 1, wn = wv & 1;   // 2x2 waves of 64x64
  // XCD-aware swizzle: id%8 = XCD (round-robin). Each XCD owns a contiguous band
  // of 16 m-tiles and iterates n fastest -> concurrent A working set ~4.3MB/XCD,
  // each A row HBM-fetched by exactly one XCD.
  const int id = blockIdx.x;                      // 1040 = 130 x 8
  const int x = id & 7, s = id >> 3;
  int mt, ntile;
  if (s < 128) { mt = x * 16 + (s >> 3); ntile = s & 7; }
  else         { mt = 128 + (s - 128);   ntile = x; }
  const int m0 = mt * 128;
  const int n0 = ntile * 128;
  const int quad = lane >> 4, r16 = lane & 15;

  v4f acc[4][4];
#pragma unroll
  for (int i = 0; i < 4; ++i)
#pragma unroll
    for (int j = 0; j < 4; ++j) { v4f z = {0.f, 0.f, 0.f, 0.f}; acc[i][j] = z; }

  for (int k0 = 0; k0 < KA; k0 += 32) {
    __syncthreads();
#pragma unroll
    for (int i = 0; i < 2; ++i) {
      const int L = i * 256 + tid;          // 512 chunks of 16B per tile
      const int r = L >> 2, c = L & 3;
      const u16* ga = A + (size_t)(m0 + r) * KA + k0 + c * 8;
      const u16* gb = Wc + (size_t)(n0 + r) * KA + k0 + c * 8;
      u16* la = &As[(size_t)(i * 256 + wv * 64) * 8];   // wave-uniform base + lane*16
      u16* lb = &Bs[(size_t)(i * 256 + wv * 64) * 8];
      __builtin_amdgcn_global_load_lds((const __attribute__((address_space(1))) void*)ga,
                                       (__attribute__((address_space(3))) void*)la, 16, 0, 0);
      __builtin_amdgcn_global_load_lds((const __attribute__((address_space(1))) void*)gb,
                                       (__attribute__((address_space(3))) void*)lb, 16, 0, 0);
    }
    __syncthreads();
    v8s af[4], bf[4];
#pragma unroll
    for (int t = 0; t < 4; ++t) {
      af[t] = *(const v8s*)&As[(wm * 64 + t * 16 + r16) * 32 + quad * 8];
      bf[t] = *(const v8s*)&Bs[(wn * 64 + t * 16 + r16) * 32 + quad * 8];
    }
#pragma unroll
    for (int mtt = 0; mtt < 4; ++mtt)
#pragma unroll
      for (int ntt = 0; ntt < 4; ++ntt)
        acc[mtt][ntt] = __builtin_amdgcn_mfma_f32_16x16x32_bf16(af[mtt], bf[ntt], acc[mtt][ntt], 0, 0, 0);
  }

  const bool relhalf = (n0 < GG);   // block-uniform
#pragma unroll
  for (int mtt = 0; mtt < 4; ++mtt) {
#pragma unroll
    for (int ntt = 0; ntt < 4; ++ntt) {
      const int n = n0 + wn * 64 + ntt * 16 + r16;           // C/D col = lane&15
      const int mbase = m0 + wm * 64 + mtt * 16 + quad * 4;  // C/D row = quad*4+reg
#pragma unroll
      for (int r = 0; r < 4; ++r) {
        const int m = mbase + r;
        float v = acc[mtt][ntt][r];
        if (relhalf) {
          v += rel_b[n];                                     // S-cols already added emb_sum/msum
          const int fo = m % FO;
          float inv = bn_w[fo] * rsqrtf(bn_rv[fo] + 1e-5f);
          out[(size_t)m * N1 + n] = (fast_tanh(v) - bn_rm[fo]) * inv + bn_b[fo];
        } else {
          v += tem_b[n - GG];
          tem_nat[(size_t)m * GG + (n - GG)] = f2bf(v);
        }
      }
    }
  }
}

// ---------- GEMM2: batched [640x544]x[544x512], fused /tem_sum + tanh + BN ----------
__global__ __launch_bounds__(256) void gemm2_kernel(
    const u16* __restrict__ A2, const u16* __restrict__ BT,
    const float* __restrict__ tsum,
    const float* __restrict__ bn_w, const float* __restrict__ bn_b,
    const float* __restrict__ bn_rm, const float* __restrict__ bn_rv,
    float* __restrict__ out) {
  __shared__ u16 As[128 * 32];
  __shared__ u16 Bs[128 * 32];
  const int tid = threadIdx.x;
  const int lane = tid & 63;
  const int wv = tid >> 6, wm = wv >> 1, wn = wv & 1;
  const int m0 = blockIdx.x * 128;       // 5 tiles over 640
  const int n0 = blockIdx.y * 128;       // 4 tiles over 512
  const int b = blockIdx.z;
  const u16* Ab = A2 + (size_t)b * M2 * K2;
  const u16* Bb = BT + (size_t)b * GG * K2;
  const int quad = lane >> 4, r16 = lane & 15;

  v4f acc[4][4];
#pragma unroll
  for (int i = 0; i < 4; ++i)
#pragma unroll
    for (int j = 0; j < 4; ++j) { v4f z = {0.f, 0.f, 0.f, 0.f}; acc[i][j] = z; }

  for (int k0 = 0; k0 < K2; k0 += 32) {
    __syncthreads();
#pragma unroll
    for (int i = 0; i < 2; ++i) {
      const int L = i * 256 + tid;
      const int r = L >> 2, c = L & 3;
      const u16* ga = Ab + (size_t)(m0 + r) * K2 + k0 + c * 8;
      const u16* gb = Bb + (size_t)(n0 + r) * K2 + k0 + c * 8;
      u16* la = &As[(size_t)(i * 256 + wv * 64) * 8];
      u16* lb = &Bs[(size_t)(i * 256 + wv * 64) * 8];
      __builtin_amdgcn_global_load_lds((const __attribute__((address_space(1))) void*)ga,
                                       (__attribute__((address_space(3))) void*)la, 16, 0, 0);
      __builtin_amdgcn_global_load_lds((const __attribute__((address_space(1))) void*)gb,
                                       (__attribute__((address_space(3))) void*)lb, 16, 0, 0);
    }
    __syncthreads();
    v8s af[4], bf[4];
#pragma unroll
    for (int t = 0; t < 4; ++t) {
      af[t] = *(const v8s*)&As[(wm * 64 + t * 16 + r16) * 32 + quad * 8];
      bf[t] = *(const v8s*)&Bs[(wn * 64 + t * 16 + r16) * 32 + quad * 8];
    }
#pragma unroll
    for (int mt = 0; mt < 4; ++mt)
#pragma unroll
      for (int nt = 0; nt < 4; ++nt)
        acc[mt][nt] = __builtin_amdgcn_mfma_f32_16x16x32_bf16(af[mt], bf[nt], acc[mt][nt], 0, 0, 0);
  }

#pragma unroll
  for (int mt = 0; mt < 4; ++mt) {
#pragma unroll
    for (int nt = 0; nt < 4; ++nt) {
      const int g = n0 + wn * 64 + nt * 16 + r16;
      const int ibase = m0 + wm * 64 + mt * 16 + quad * 4;
#pragma unroll
      for (int r = 0; r < 4; ++r) {
        const int i = ibase + r;
        if (i < FO) {
          float v = acc[mt][nt][r] / tsum[(size_t)b * FO + i];
          float inv = bn_w[i] * rsqrtf(bn_rv[i] + 1e-5f);
          out[((size_t)(b * FO + i)) * N1 + GG + g] =
              (fast_tanh(v) - bn_rm[i]) * inv + bn_b[i];
        }
      }
    }
  }
}

extern "C" void kernel_launch(void* const* d_in, const int* in_sizes, int n_in,
                              void* d_out, int out_size, void* d_ws, size_t ws_size,
                              hipStream_t stream) {
  const float* region_feats = (const float*)d_in[0];
  // d_in[1] region_masks: unused by reference
  const int* rel_feats = (const int*)d_in[2];
  const float* tem_feats = (const float*)d_in[3];
  const float* rel_W = (const float*)d_in[4];
  const float* rel_b = (const float*)d_in[5];
  const float* rel_emb = (const float*)d_in[6];
  const float* tem_W = (const float*)d_in[7];
  const float* tem_b = (const float*)d_in[8];
  const float* bn_w = (const float*)d_in[9];
  const float* bn_b = (const float*)d_in[10];
  const float* bn_rm = (const float*)d_in[11];
  const float* bn_rv = (const float*)d_in[12];
  float* out = (float*)d_out;

  // Workspace layout (liveness aliasing): total 114.0 MB
  char* base = (char*)d_ws;
  u16* A1 = (u16*)base;                                   // [16640][2112] bf16 : 70,287,360
  u16* BT = (u16*)base;                                   // aliases A1 (dead after GEMM1)
  u16* Wc = (u16*)(base + 70287360);                      // [1024][2112] bf16 : 4,325,376
  u16* A2 = (u16*)(base + 74612736);                      // [32][640][544] bf16: 22,282,240
  u16* tem_nat = (u16*)(base + 96894976);                 // [16640][512] bf16 : 17,039,360
  float* tsum = (float*)(base + 113934336);               // [32*520] f32      : 66,560

  cast8_kernel<<<16640, 256, 0, stream>>>(region_feats, rel_feats, A1);
  castw_kernel<<<1024, 256, 0, stream>>>(rel_W, tem_W, rel_emb, Wc);
  casta2_kernel<<<5120, 256, 0, stream>>>(tem_feats, A2, tsum);
  gemm1_kernel<<<1040, 256, 0, stream>>>(A1, Wc, rel_b, tem_b,
                                         bn_w, bn_b, bn_rm, bn_rv, out, tem_nat);
  transp_kernel<<<dim3(9, 8, 32), dim3(32, 8), 0, stream>>>(tem_nat, BT);
  gemm2_kernel<<<dim3(5, 4, 32), 256, 0, stream>>>(A2, BT, tsum,
                                                   bn_w, bn_b, bn_rm, bn_rv, out);
}

// Round 3
// 451.476 us; speedup vs baseline: 1.0961x; 1.0228x over previous
//
#include <hip/hip_runtime.h>
#include <stdint.h>

// Problem constants
#define BB 32
#define FO 520          // F*O
#define M1 16640        // BB*FO
#define KIN 2048        // IN
#define KA 2112         // IN + 64 (S-matrix columns folded into K)
#define N1 1024         // 2*G (concatenated rel|tem)
#define GG 512          // G
#define K2P 576         // 520 padded to mult of 64 (BK=64 loop)
#define M2 640          // 520 padded to mult of 128

typedef unsigned short u16;
typedef short v8s __attribute__((ext_vector_type(8)));   // 8 bf16 (4 VGPRs) MFMA A/B frag
typedef float v4f __attribute__((ext_vector_type(4)));   // MFMA C/D frag

__device__ __forceinline__ u16 f2bf(float f) {
  union { float f; unsigned u; } v; v.f = f;
  unsigned r = v.u + 0x7fffu + ((v.u >> 16) & 1u);   // RNE, inputs finite
  return (u16)(r >> 16);
}

__device__ __forceinline__ float fast_tanh(float x) {
  float cx = fminf(fmaxf(x, -15.f), 15.f);
  float e = __expf(2.f * cx);
  return (e - 1.f) / (e + 1.f);
}

// ---------- prep: cast region_feats (+S cols) -> A1, pack rel_W|emb^T / tem_W|0 -> Wc ----------
// S[m,l] = count_j(rel[m,j]==l+1) / msum[m]  (l<52): emb lookup folded into GEMM K-ext.
__global__ void prep_kernel(const float* __restrict__ rf, const int* __restrict__ rel,
                            const float* __restrict__ relW, const float* __restrict__ temW,
                            const float* __restrict__ emb,
                            u16* __restrict__ A1, u16* __restrict__ Wc) {
  const int blk = blockIdx.x;
  const int t = threadIdx.x;         // 256 -> one row of 2048
  const float* src;
  u16* orow;
  if (blk < M1) {
    src = rf + (size_t)blk * KIN;
    orow = A1 + (size_t)blk * KA;
  } else {
    const int n = blk - M1;          // 0..1023
    src = (n < GG) ? (relW + (size_t)n * KIN) : (temW + (size_t)(n - GG) * KIN);
    orow = Wc + (size_t)n * KA;
  }
  const float4* p = (const float4*)src;
  float4 a = p[2 * t], b = p[2 * t + 1];
  v8s v;
  v[0] = (short)f2bf(a.x); v[1] = (short)f2bf(a.y);
  v[2] = (short)f2bf(a.z); v[3] = (short)f2bf(a.w);
  v[4] = (short)f2bf(b.x); v[5] = (short)f2bf(b.y);
  v[6] = (short)f2bf(b.z); v[7] = (short)f2bf(b.w);
  *(v8s*)(orow + t * 8) = v;
  if (t < 64) {                      // wave 0: K-extension columns
    float sval = 0.f;
    if (blk < M1) {                  // S row
      const int* rp = rel + (size_t)blk * 20;
      int cnt = 0, ms = 0;
#pragma unroll
      for (int j = 0; j < 20; ++j) { // block-uniform -> scalar loads
        int ix = rp[j];
        cnt += (ix == t + 1);
        ms += (ix > 0);
      }
      if (t < 52 && ms > 0) sval = (float)cnt / (float)ms;
    } else {
      const int n = blk - M1;
      if (n < GG && t < 52) sval = emb[(size_t)(t + 1) * GG + n];
    }
    orow[KIN + t] = f2bf(sval);
  }
}

// ---------- tem_feats fp32 -> A2 [32][640][576] bf16 (zero-padded) + row sums ----------
__global__ void casta2_kernel(const float* __restrict__ tem, u16* __restrict__ A2,
                              float* __restrict__ tsum) {
  const int w = threadIdx.x >> 6;                 // wave 0..3 -> one row each
  const int l = threadIdx.x & 63;
  const int row = blockIdx.x * 4 + w;             // [32][640]
  const int b = row / M2, i = row % M2;
  u16* orow = A2 + (size_t)row * K2P;
  v8s z = {0, 0, 0, 0, 0, 0, 0, 0};
  if (i >= FO) {                                  // pad row: all 72 chunks zero
    *(v8s*)(orow + l * 8) = z;
    if (l < 8) *(v8s*)(orow + (64 + l) * 8) = z;
    return;
  }
  const float* srow = tem + ((size_t)b * FO + i) * FO;   // row base 2080B: 16B-aligned
  float s = 0.f;
  {
    float4 a = *(const float4*)(srow + 8 * l);
    float4 bb = *(const float4*)(srow + 8 * l + 4);
    s += a.x + a.y + a.z + a.w + bb.x + bb.y + bb.z + bb.w;
    v8s v;
    v[0] = (short)f2bf(a.x); v[1] = (short)f2bf(a.y);
    v[2] = (short)f2bf(a.z); v[3] = (short)f2bf(a.w);
    v[4] = (short)f2bf(bb.x); v[5] = (short)f2bf(bb.y);
    v[6] = (short)f2bf(bb.z); v[7] = (short)f2bf(bb.w);
    *(v8s*)(orow + l * 8) = v;
  }
  if (l < 8) {
    if (l == 0) {                                 // chunk 64: floats 512..519
      float4 a = *(const float4*)(srow + 512);
      float4 bb = *(const float4*)(srow + 516);
      s += a.x + a.y + a.z + a.w + bb.x + bb.y + bb.z + bb.w;
      v8s v;
      v[0] = (short)f2bf(a.x); v[1] = (short)f2bf(a.y);
      v[2] = (short)f2bf(a.z); v[3] = (short)f2bf(a.w);
      v[4] = (short)f2bf(bb.x); v[5] = (short)f2bf(bb.y);
      v[6] = (short)f2bf(bb.z); v[7] = (short)f2bf(bb.w);
      *(v8s*)(orow + 512) = v;
    } else {
      *(v8s*)(orow + (64 + l) * 8) = z;
    }
  }
#pragma unroll
  for (int off = 32; off > 0; off >>= 1) s += __shfl_down(s, off);
  if (l == 0) tsum[(size_t)b * FO + i] = s;
}

// ---------- GEMM1: [16640x2112]x[2112x1024] bf16 MFMA, BK=64, xor-swizzled LDS ----------
// rel half -> tanh+BN -> out ; tem half -> +bias -> BT [32][512][576] (transpose via LDS)
__global__ __launch_bounds__(256) void gemm1_kernel(
    const u16* __restrict__ A, const u16* __restrict__ Wc,
    const float* __restrict__ rel_b, const float* __restrict__ tem_b,
    const float* __restrict__ bn_w, const float* __restrict__ bn_b,
    const float* __restrict__ bn_rm, const float* __restrict__ bn_rv,
    float* __restrict__ out, u16* __restrict__ BT) {
  __shared__ u16 smem[128 * 132];                 // 33792B: K-loop uses 32KB, epilogue 33792B
  u16* As = smem;                                 // [128][64]
  u16* Bs = smem + 128 * 64;
  const int tid = threadIdx.x;
  const int lane = tid & 63;
  const int wv = tid >> 6, wm = wv >> 1, wn = wv & 1;   // 2x2 waves of 64x64
  // XCD swizzle: id%8 = XCD; each XCD owns a band of m-tiles, n fastest.
  const int id = blockIdx.x;                      // 1040 = 130 x 8
  const int x = id & 7, s = id >> 3;
  int mt, ntile;
  if (s < 128) { mt = x * 16 + (s >> 3); ntile = s & 7; }
  else         { mt = 128 + (s - 128);   ntile = x; }
  const int m0 = mt * 128, n0 = ntile * 128;
  const int quad = lane >> 4, r16 = lane & 15;

  v4f acc[4][4];
#pragma unroll
  for (int i = 0; i < 4; ++i)
#pragma unroll
    for (int j = 0; j < 4; ++j) { v4f z = {0.f, 0.f, 0.f, 0.f}; acc[i][j] = z; }

  for (int k0 = 0; k0 < KA; k0 += 64) {
    __syncthreads();
#pragma unroll
    for (int i = 0; i < 4; ++i) {
      const int L = i * 256 + tid;          // 1024 chunks of 16B per tile
      const int r = L >> 3;
      const int c = (L & 7) ^ (r & 7);      // xor-swizzle: LDS slot (r,L&7) holds global chunk c
      const u16* ga = A + (size_t)(m0 + r) * KA + k0 + c * 8;
      const u16* gb = Wc + (size_t)(n0 + r) * KA + k0 + c * 8;
      u16* la = &As[(size_t)(i * 256 + wv * 64) * 8];   // wave-uniform base + lane*16
      u16* lb = &Bs[(size_t)(i * 256 + wv * 64) * 8];
      __builtin_amdgcn_global_load_lds((const __attribute__((address_space(1))) void*)ga,
                                       (__attribute__((address_space(3))) void*)la, 16, 0, 0);
      __builtin_amdgcn_global_load_lds((const __attribute__((address_space(1))) void*)gb,
                                       (__attribute__((address_space(3))) void*)lb, 16, 0, 0);
    }
    __syncthreads();
#pragma unroll
    for (int ks = 0; ks < 2; ++ks) {
      v8s af[4], bf[4];
#pragma unroll
      for (int t4 = 0; t4 < 4; ++t4) {
        const int ra = wm * 64 + t4 * 16 + r16;
        const int rb = wn * 64 + t4 * 16 + r16;
        af[t4] = *(const v8s*)&As[ra * 64 + (((ks * 4 + quad) ^ (ra & 7)) * 8)];
        bf[t4] = *(const v8s*)&Bs[rb * 64 + (((ks * 4 + quad) ^ (rb & 7)) * 8)];
      }
#pragma unroll
      for (int mtt = 0; mtt < 4; ++mtt)
#pragma unroll
        for (int ntt = 0; ntt < 4; ++ntt)
          acc[mtt][ntt] = __builtin_amdgcn_mfma_f32_16x16x32_bf16(af[mtt], bf[ntt], acc[mtt][ntt], 0, 0, 0);
    }
  }

  if (n0 < GG) {        // ---- rel half: +bias, tanh, BN -> out (block-uniform branch)
#pragma unroll
    for (int mtt = 0; mtt < 4; ++mtt) {
      const int mb = m0 + wm * 64 + mtt * 16 + quad * 4;
      const int bb = mb / FO;
      const int fo0 = mb - bb * FO;          // mb mult of 4, FO mult of 4: quad never crosses
#pragma unroll
      for (int ntt = 0; ntt < 4; ++ntt) {
        const int n = n0 + wn * 64 + ntt * 16 + r16;
        const float rbn = rel_b[n];
#pragma unroll
        for (int r = 0; r < 4; ++r) {
          const int fo = fo0 + r;
          const float inv = bn_w[fo] * rsqrtf(bn_rv[fo] + 1e-5f);
          out[(size_t)(mb + r) * N1 + n] =
              (fast_tanh(acc[mtt][ntt][r] + rbn) - bn_rm[fo]) * inv + bn_b[fo];
        }
      }
    }
  } else {              // ---- tem half: +bias -> bf16 -> LDS transpose -> BT coalesced
    __syncthreads();    // all waves done reading As/Bs
#pragma unroll
    for (int mtt = 0; mtt < 4; ++mtt) {
      const int il = wm * 64 + mtt * 16 + quad * 4;
#pragma unroll
      for (int ntt = 0; ntt < 4; ++ntt) {
        const int gl = wn * 64 + ntt * 16 + r16;
        const float tb = tem_b[(n0 - GG) + gl];
        ushort4 w;
        w.x = f2bf(acc[mtt][ntt][0] + tb);
        w.y = f2bf(acc[mtt][ntt][1] + tb);
        w.z = f2bf(acc[mtt][ntt][2] + tb);
        w.w = f2bf(acc[mtt][ntt][3] + tb);
        *(ushort4*)&smem[gl * 132 + il] = w;   // row stride 132 u16: bank spread
      }
    }
    __syncthreads();
    const int gl = tid >> 1, seg = tid & 1;     // 128 g-rows x 2 half-rows of 64 u16
    const int g = (n0 - GG) + gl;
    const u16* src = &smem[gl * 132 + seg * 64];
    const int mbase = m0 + seg * 64;
#pragma unroll
    for (int ch = 0; ch < 8; ++ch) {
      const int m = mbase + ch * 8;
      const int b1 = m / FO;                    // 8-runs never cross b (520 % 8 == 0)
      const int i1 = m - b1 * FO;
      ushort4 lo = *(const ushort4*)(src + ch * 8);
      ushort4 hi = *(const ushort4*)(src + ch * 8 + 4);
      u16* dst = BT + ((size_t)(b1 * GG + g)) * K2P + i1;
      *(ushort4*)dst = lo;
      *(ushort4*)(dst + 4) = hi;
    }
  }
}

// ---------- GEMM2: batched [640x576]x[576x512], BK=64, fused /tem_sum + tanh + BN ----------
__global__ __launch_bounds__(256) void gemm2_kernel(
    const u16* __restrict__ A2, const u16* __restrict__ BT,
    const float* __restrict__ tsum,
    const float* __restrict__ bn_w, const float* __restrict__ bn_b,
    const float* __restrict__ bn_rm, const float* __restrict__ bn_rv,
    float* __restrict__ out) {
  __shared__ u16 smem[2 * 128 * 64];
  u16* As = smem;
  u16* Bs = smem + 128 * 64;
  const int tid = threadIdx.x;
  const int lane = tid & 63;
  const int wv = tid >> 6, wm = wv >> 1, wn = wv & 1;
  const int m0 = blockIdx.x * 128;       // 5 tiles over 640
  const int n0 = blockIdx.y * 128;       // 4 tiles over 512
  const int b = blockIdx.z;
  const u16* Ab = A2 + (size_t)b * M2 * K2P;
  const u16* Bb = BT + (size_t)b * GG * K2P;
  const int quad = lane >> 4, r16 = lane & 15;

  v4f acc[4][4];
#pragma unroll
  for (int i = 0; i < 4; ++i)
#pragma unroll
    for (int j = 0; j < 4; ++j) { v4f z = {0.f, 0.f, 0.f, 0.f}; acc[i][j] = z; }

  for (int k0 = 0; k0 < K2P; k0 += 64) {       // 9 iterations
    __syncthreads();
#pragma unroll
    for (int i = 0; i < 4; ++i) {
      const int L = i * 256 + tid;
      const int r = L >> 3;
      const int c = (L & 7) ^ (r & 7);
      const u16* ga = Ab + (size_t)(m0 + r) * K2P + k0 + c * 8;
      const u16* gb = Bb + (size_t)(n0 + r) * K2P + k0 + c * 8;
      u16* la = &As[(size_t)(i * 256 + wv * 64) * 8];
      u16* lb = &Bs[(size_t)(i * 256 + wv * 64) * 8];
      __builtin_amdgcn_global_load_lds((const __attribute__((address_space(1))) void*)ga,
                                       (__attribute__((address_space(3))) void*)la, 16, 0, 0);
      __builtin_amdgcn_global_load_lds((const __attribute__((address_space(1))) void*)gb,
                                       (__attribute__((address_space(3))) void*)lb, 16, 0, 0);
    }
    __syncthreads();
#pragma unroll
    for (int ks = 0; ks < 2; ++ks) {
      v8s af[4], bf[4];
#pragma unroll
      for (int t4 = 0; t4 < 4; ++t4) {
        const int ra = wm * 64 + t4 * 16 + r16;
        const int rb = wn * 64 + t4 * 16 + r16;
        af[t4] = *(const v8s*)&As[ra * 64 + (((ks * 4 + quad) ^ (ra & 7)) * 8)];
        bf[t4] = *(const v8s*)&Bs[rb * 64 + (((ks * 4 + quad) ^ (rb & 7)) * 8)];
      }
#pragma unroll
      for (int mtt = 0; mtt < 4; ++mtt)
#pragma unroll
        for (int ntt = 0; ntt < 4; ++ntt)
          acc[mtt][ntt] = __builtin_amdgcn_mfma_f32_16x16x32_bf16(af[mtt], bf[ntt], acc[mtt][ntt], 0, 0, 0);
    }
  }

#pragma unroll
  for (int mtt = 0; mtt < 4; ++mtt) {
#pragma unroll
    for (int ntt = 0; ntt < 4; ++ntt) {
      const int g = n0 + wn * 64 + ntt * 16 + r16;
      const int ibase = m0 + wm * 64 + mtt * 16 + quad * 4;
#pragma unroll
      for (int r = 0; r < 4; ++r) {
        const int i = ibase + r;
        if (i < FO) {
          float v = acc[mtt][ntt][r] / tsum[(size_t)b * FO + i];
          float inv = bn_w[i] * rsqrtf(bn_rv[i] + 1e-5f);
          out[((size_t)(b * FO + i)) * N1 + GG + g] =
              (fast_tanh(v) - bn_rm[i]) * inv + bn_b[i];
        }
      }
    }
  }
}

extern "C" void kernel_launch(void* const* d_in, const int* in_sizes, int n_in,
                              void* d_out, int out_size, void* d_ws, size_t ws_size,
                              hipStream_t stream) {
  const float* region_feats = (const float*)d_in[0];
  // d_in[1] region_masks: unused by reference
  const int* rel_feats = (const int*)d_in[2];
  const float* tem_feats = (const float*)d_in[3];
  const float* rel_W = (const float*)d_in[4];
  const float* rel_b = (const float*)d_in[5];
  const float* rel_emb = (const float*)d_in[6];
  const float* tem_W = (const float*)d_in[7];
  const float* tem_b = (const float*)d_in[8];
  const float* bn_w = (const float*)d_in[9];
  const float* bn_b = (const float*)d_in[10];
  const float* bn_rm = (const float*)d_in[11];
  const float* bn_rv = (const float*)d_in[12];
  float* out = (float*)d_out;

  // Workspace layout: total 117.1 MB (no aliasing needed this round)
  char* base = (char*)d_ws;
  u16* A1 = (u16*)base;                                   // [16640][2112] bf16 : 70,287,360
  u16* Wc = (u16*)(base + 70287360);                      // [1024][2112] bf16  :  4,325,376
  u16* A2 = (u16*)(base + 74612736);                      // [32][640][576] bf16: 23,592,960
  u16* BT = (u16*)(base + 98205696);                      // [32][512][576] bf16: 18,874,368
  float* tsum = (float*)(base + 117080064);               // [32*520] f32       :     66,560

  prep_kernel<<<M1 + 1024, 256, 0, stream>>>(region_feats, rel_feats,
                                             rel_W, tem_W, rel_emb, A1, Wc);
  casta2_kernel<<<5120, 256, 0, stream>>>(tem_feats, A2, tsum);
  gemm1_kernel<<<1040, 256, 0, stream>>>(A1, Wc, rel_b, tem_b,
                                         bn_w, bn_b, bn_rm, bn_rv, out, BT);
  gemm2_kernel<<<dim3(5, 4, 32), 256, 0, stream>>>(A2, BT, tsum,
                                                   bn_w, bn_b, bn_rm, bn_rv, out);
}

// Round 4
// 442.758 us; speedup vs baseline: 1.1177x; 1.0197x over previous
//
#include <hip/hip_runtime.h>
#include <stdint.h>

// Problem constants
#define BB 32
#define FO 520          // F*O
#define M1 16640        // BB*FO
#define KIN 2048        // IN
#define KA 2112         // IN + 64 (S-matrix columns folded into K)
#define N1 1024         // 2*G (concatenated rel|tem)
#define GG 512          // G
#define K2P 576         // 520 padded to mult of 64
#define M2 640          // 520 padded to mult of 64/128

typedef unsigned short u16;
typedef short v8s __attribute__((ext_vector_type(8)));   // 8 bf16 MFMA A/B frag
typedef float v4f __attribute__((ext_vector_type(4)));   // MFMA C/D frag

__device__ __forceinline__ u16 f2bf(float f) {
  union { float f; unsigned u; } v; v.f = f;
  unsigned r = v.u + 0x7fffu + ((v.u >> 16) & 1u);   // RNE, inputs finite
  return (u16)(r >> 16);
}

__device__ __forceinline__ float fast_tanh(float x) {
  float cx = fminf(fmaxf(x, -15.f), 15.f);
  float e = __expf(2.f * cx);
  return (e - 1.f) / (e + 1.f);
}

// ---------- prep_all: A1 rows | Wc rows | A2+tsum rows, one dispatch ----------
__global__ void prep_all_kernel(const float* __restrict__ rf, const int* __restrict__ rel,
                                const float* __restrict__ relW, const float* __restrict__ temW,
                                const float* __restrict__ emb, const float* __restrict__ tem,
                                u16* __restrict__ A1, u16* __restrict__ Wc,
                                u16* __restrict__ A2, float* __restrict__ tsum) {
  const int blk = blockIdx.x;
  const int t = threadIdx.x;
  if (blk < M1 + 1024) {               // ---- A1 / Wc row (2048 f32 -> bf16, + 64 K-ext)
    const float* src;
    u16* orow;
    if (blk < M1) { src = rf + (size_t)blk * KIN; orow = A1 + (size_t)blk * KA; }
    else {
      const int n = blk - M1;
      src = (n < GG) ? (relW + (size_t)n * KIN) : (temW + (size_t)(n - GG) * KIN);
      orow = Wc + (size_t)n * KA;
    }
    const float4* p = (const float4*)src;
    float4 a = p[2 * t], b = p[2 * t + 1];
    v8s v;
    v[0] = (short)f2bf(a.x); v[1] = (short)f2bf(a.y);
    v[2] = (short)f2bf(a.z); v[3] = (short)f2bf(a.w);
    v[4] = (short)f2bf(b.x); v[5] = (short)f2bf(b.y);
    v[6] = (short)f2bf(b.z); v[7] = (short)f2bf(b.w);
    *(v8s*)(orow + t * 8) = v;
    if (t < 64) {                      // K-extension columns
      float sval = 0.f;
      if (blk < M1) {                  // S[m,l] = count(idx==l+1)/msum
        const int* rp = rel + (size_t)blk * 20;
        int cnt = 0, ms = 0;
#pragma unroll
        for (int j = 0; j < 20; ++j) { int ix = rp[j]; cnt += (ix == t + 1); ms += (ix > 0); }
        if (t < 52 && ms > 0) sval = (float)cnt / (float)ms;
      } else {
        const int n = blk - M1;
        if (n < GG && t < 52) sval = emb[(size_t)(t + 1) * GG + n];
      }
      orow[KIN + t] = f2bf(sval);
    }
    return;
  }
  // ---- casta2 part: tem_feats -> A2 [32][640][576] bf16 + row sums
  const int w = t >> 6, l = t & 63;
  const int row = (blk - (M1 + 1024)) * 4 + w;   // [32][640]
  const int b = row / M2, i = row % M2;
  u16* orow = A2 + (size_t)row * K2P;
  v8s z = {0, 0, 0, 0, 0, 0, 0, 0};
  if (i >= FO) {
    *(v8s*)(orow + l * 8) = z;
    if (l < 8) *(v8s*)(orow + (64 + l) * 8) = z;
    return;
  }
  const float* srow = tem + ((size_t)b * FO + i) * FO;
  float s = 0.f;
  {
    float4 a = *(const float4*)(srow + 8 * l);
    float4 bb = *(const float4*)(srow + 8 * l + 4);
    s += a.x + a.y + a.z + a.w + bb.x + bb.y + bb.z + bb.w;
    v8s v;
    v[0] = (short)f2bf(a.x); v[1] = (short)f2bf(a.y);
    v[2] = (short)f2bf(a.z); v[3] = (short)f2bf(a.w);
    v[4] = (short)f2bf(bb.x); v[5] = (short)f2bf(bb.y);
    v[6] = (short)f2bf(bb.z); v[7] = (short)f2bf(bb.w);
    *(v8s*)(orow + l * 8) = v;
  }
  if (l < 8) {
    if (l == 0) {
      float4 a = *(const float4*)(srow + 512);
      float4 bb = *(const float4*)(srow + 516);
      s += a.x + a.y + a.z + a.w + bb.x + bb.y + bb.z + bb.w;
      v8s v;
      v[0] = (short)f2bf(a.x); v[1] = (short)f2bf(a.y);
      v[2] = (short)f2bf(a.z); v[3] = (short)f2bf(a.w);
      v[4] = (short)f2bf(bb.x); v[5] = (short)f2bf(bb.y);
      v[6] = (short)f2bf(bb.z); v[7] = (short)f2bf(bb.w);
      *(v8s*)(orow + 512) = v;
    } else {
      *(v8s*)(orow + (64 + l) * 8) = z;
    }
  }
#pragma unroll
  for (int off = 32; off > 0; off >>= 1) s += __shfl_down(s, off);
  if (l == 0) tsum[(size_t)b * FO + i] = s;
}

// ---------- GEMM1: [16640x2112]x[2112x1024] bf16 MFMA, BK=32, swizzled LDS ----------
// rel half -> tanh+BN -> out ; tem half -> +bias -> BT [32][512][576] (LDS transpose)
__global__ __launch_bounds__(256) void gemm1_kernel(
    const u16* __restrict__ A, const u16* __restrict__ Wc,
    const float* __restrict__ rel_b, const float* __restrict__ tem_b,
    const float* __restrict__ bn_w, const float* __restrict__ bn_b,
    const float* __restrict__ bn_rm, const float* __restrict__ bn_rv,
    float* __restrict__ out, u16* __restrict__ BT) {
  __shared__ u16 smem[8704];                      // 17408B: K-loop 16KB; epi phase 64x136
  u16* As = smem;                                 // [128][32]
  u16* Bs = smem + 4096;
  const int tid = threadIdx.x;
  const int lane = tid & 63;
  const int wv = tid >> 6, wm = wv >> 1, wn = wv & 1;   // 2x2 waves of 64x64
  const int id = blockIdx.x;                      // 1040 = 130 x 8; XCD swizzle
  const int x = id & 7, s = id >> 3;
  int mt, ntile;
  if (s < 128) { mt = x * 16 + (s >> 3); ntile = s & 7; }
  else         { mt = 128 + (s - 128);   ntile = x; }
  const int m0 = mt * 128, n0 = ntile * 128;
  const int quad = lane >> 4, r16 = lane & 15;

  // staging pointers: chunk (r, slot s) holds global chunk c = s ^ ((r>>1)&3)
  const u16* ga[2]; const u16* gb[2];
  u16* la[2]; u16* lb[2];
#pragma unroll
  for (int i = 0; i < 2; ++i) {
    const int L = i * 256 + tid;
    const int r = L >> 2, sl = L & 3;
    const int c = sl ^ ((r >> 1) & 3);
    ga[i] = A + (size_t)(m0 + r) * KA + c * 8;
    gb[i] = Wc + (size_t)(n0 + r) * KA + c * 8;
    la[i] = &As[(size_t)(i * 256 + wv * 64) * 8];
    lb[i] = &Bs[(size_t)(i * 256 + wv * 64) * 8];
  }

  v4f acc[4][4];
#pragma unroll
  for (int i = 0; i < 4; ++i)
#pragma unroll
    for (int j = 0; j < 4; ++j) { v4f z = {0.f, 0.f, 0.f, 0.f}; acc[i][j] = z; }

  for (int k0 = 0; k0 < KA; k0 += 32) {           // 66 iterations
    __syncthreads();
#pragma unroll
    for (int i = 0; i < 2; ++i) {
      __builtin_amdgcn_global_load_lds((const __attribute__((address_space(1))) void*)ga[i],
                                       (__attribute__((address_space(3))) void*)la[i], 16, 0, 0);
      __builtin_amdgcn_global_load_lds((const __attribute__((address_space(1))) void*)gb[i],
                                       (__attribute__((address_space(3))) void*)lb[i], 16, 0, 0);
      ga[i] += 32; gb[i] += 32;
    }
    __syncthreads();
    v8s af[4], bf[4];
#pragma unroll
    for (int t4 = 0; t4 < 4; ++t4) {
      const int ra = wm * 64 + t4 * 16 + r16;
      const int rb = wn * 64 + t4 * 16 + r16;
      af[t4] = *(const v8s*)&As[ra * 32 + ((quad ^ ((ra >> 1) & 3)) * 8)];
      bf[t4] = *(const v8s*)&Bs[rb * 32 + ((quad ^ ((rb >> 1) & 3)) * 8)];
    }
#pragma unroll
    for (int mtt = 0; mtt < 4; ++mtt)
#pragma unroll
      for (int ntt = 0; ntt < 4; ++ntt)
        acc[mtt][ntt] = __builtin_amdgcn_mfma_f32_16x16x32_bf16(af[mtt], bf[ntt], acc[mtt][ntt], 0, 0, 0);
  }

  if (n0 < GG) {        // ---- rel half: +bias, tanh, BN -> out
#pragma unroll
    for (int mtt = 0; mtt < 4; ++mtt) {
      const int mb = m0 + wm * 64 + mtt * 16 + quad * 4;
      const int bb = mb / FO;
      const int fo0 = mb - bb * FO;               // quad never crosses batch (4 | FO)
      float inv[4], rm[4], bofs[4];
#pragma unroll
      for (int r = 0; r < 4; ++r) {
        const int fo = fo0 + r;
        inv[r] = bn_w[fo] * rsqrtf(bn_rv[fo] + 1e-5f);
        rm[r] = bn_rm[fo]; bofs[r] = bn_b[fo];
      }
#pragma unroll
      for (int ntt = 0; ntt < 4; ++ntt) {
        const int n = n0 + wn * 64 + ntt * 16 + r16;
        const float rbn = rel_b[n];
#pragma unroll
        for (int r = 0; r < 4; ++r) {
          float val = (fast_tanh(acc[mtt][ntt][r] + rbn) - rm[r]) * inv[r] + bofs[r];
          __builtin_nontemporal_store(val, out + (size_t)(mb + r) * N1 + n);
        }
      }
    }
  } else {              // ---- tem half: +bias -> bf16 -> LDS transpose -> BT (2 phases)
    __syncthreads();    // all waves done reading As/Bs (smem reused)
#pragma unroll
    for (int p = 0; p < 2; ++p) {
      if (p) __syncthreads();                     // phase0 readers done
      if (wn == p) {
#pragma unroll
        for (int mtt = 0; mtt < 4; ++mtt) {
          const int il = wm * 64 + mtt * 16 + quad * 4;
#pragma unroll
          for (int ntt = 0; ntt < 4; ++ntt) {
            const int gl = ntt * 16 + r16;        // local g row 0..63
            const float tb = tem_b[(n0 - GG) + p * 64 + gl];
            ushort4 w;
            w.x = f2bf(acc[mtt][ntt][0] + tb);
            w.y = f2bf(acc[mtt][ntt][1] + tb);
            w.z = f2bf(acc[mtt][ntt][2] + tb);
            w.w = f2bf(acc[mtt][ntt][3] + tb);
            *(ushort4*)&smem[gl * 136 + il] = w;
          }
        }
      }
      __syncthreads();
      // 64 g-rows x 128 i: 4 passes, 256B contiguous stores
#pragma unroll
      for (int pass = 0; pass < 4; ++pass) {
        const int gl = pass * 16 + (tid >> 4);    // 0..63
        const int ch = tid & 15;
        const int m = m0 + ch * 8;
        const int b1 = m / FO;                    // 8-runs never cross b (520 % 8 == 0)
        const int i1 = m - b1 * FO;
        v8s val = *(const v8s*)&smem[gl * 136 + ch * 8];
        const int g = (n0 - GG) + p * 64 + gl;
        *(v8s*)(BT + ((size_t)(b1 * GG + g)) * K2P + i1) = val;
      }
    }
  }
}

// ---------- GEMM2: batched [640x576]x[576x512], 64x64 tiles, fused epilogue ----------
__global__ __launch_bounds__(256) void gemm2_kernel(
    const u16* __restrict__ A2, const u16* __restrict__ BT,
    const float* __restrict__ tsum,
    const float* __restrict__ bn_w, const float* __restrict__ bn_b,
    const float* __restrict__ bn_rm, const float* __restrict__ bn_rv,
    float* __restrict__ out) {
  __shared__ u16 smem[2 * 64 * 64];               // 16KB
  u16* As = smem;
  u16* Bs = smem + 4096;
  const int tid = threadIdx.x;
  const int lane = tid & 63;
  const int wv = tid >> 6, wm = wv >> 1, wn = wv & 1;   // 2x2 waves of 32x32
  const int m0 = blockIdx.x * 64;                 // 10 tiles over 640
  const int n0 = blockIdx.y * 64;                 // 8 tiles over 512
  const int b = blockIdx.z;
  const u16* Ab = A2 + (size_t)b * M2 * K2P;
  const u16* Bb = BT + (size_t)b * GG * K2P;
  const int quad = lane >> 4, r16 = lane & 15;

  const u16* gp[4]; u16* lp[4];
#pragma unroll
  for (int i = 0; i < 4; ++i) {
    const int L = i * 256 + tid;
    const int tile = L >> 9;                      // 0=A, 1=B
    const int idx = L & 511;
    const int r = idx >> 3, sl = idx & 7;
    const int c = sl ^ (r & 7);
    gp[i] = (tile ? (Bb + (size_t)(n0 + r) * K2P) : (Ab + (size_t)(m0 + r) * K2P)) + c * 8;
    lp[i] = (tile ? Bs : As) + (size_t)((i & 1) * 256 + wv * 64) * 8;
  }

  v4f acc[2][2];
#pragma unroll
  for (int i = 0; i < 2; ++i)
#pragma unroll
    for (int j = 0; j < 2; ++j) { v4f z = {0.f, 0.f, 0.f, 0.f}; acc[i][j] = z; }

  for (int k0 = 0; k0 < K2P; k0 += 64) {          // 9 iterations
    __syncthreads();
#pragma unroll
    for (int i = 0; i < 4; ++i) {
      __builtin_amdgcn_global_load_lds((const __attribute__((address_space(1))) void*)gp[i],
                                       (__attribute__((address_space(3))) void*)lp[i], 16, 0, 0);
      gp[i] += 64;
    }
    __syncthreads();
#pragma unroll
    for (int ks = 0; ks < 2; ++ks) {
      v8s af[2], bf[2];
#pragma unroll
      for (int t4 = 0; t4 < 2; ++t4) {
        const int ra = wm * 32 + t4 * 16 + r16;
        const int rb = wn * 32 + t4 * 16 + r16;
        af[t4] = *(const v8s*)&As[ra * 64 + (((ks * 4 + quad) ^ (ra & 7)) * 8)];
        bf[t4] = *(const v8s*)&Bs[rb * 64 + (((ks * 4 + quad) ^ (rb & 7)) * 8)];
      }
#pragma unroll
      for (int mtt = 0; mtt < 2; ++mtt)
#pragma unroll
        for (int ntt = 0; ntt < 2; ++ntt)
          acc[mtt][ntt] = __builtin_amdgcn_mfma_f32_16x16x32_bf16(af[mtt], bf[ntt], acc[mtt][ntt], 0, 0, 0);
    }
  }

#pragma unroll
  for (int mtt = 0; mtt < 2; ++mtt) {
    const int ibase = m0 + wm * 32 + mtt * 16 + quad * 4;
    float ts[4], inv[4], rm[4], bofs[4];
#pragma unroll
    for (int r = 0; r < 4; ++r) {
      const int i = ibase + r;
      if (i < FO) {
        ts[r] = 1.f / tsum[(size_t)b * FO + i];
        inv[r] = bn_w[i] * rsqrtf(bn_rv[i] + 1e-5f);
        rm[r] = bn_rm[i]; bofs[r] = bn_b[i];
      }
    }
#pragma unroll
    for (int ntt = 0; ntt < 2; ++ntt) {
      const int g = n0 + wn * 32 + ntt * 16 + r16;
#pragma unroll
      for (int r = 0; r < 4; ++r) {
        const int i = ibase + r;
        if (i < FO) {
          float val = (fast_tanh(acc[mtt][ntt][r] * ts[r]) - rm[r]) * inv[r] + bofs[r];
          __builtin_nontemporal_store(val, out + ((size_t)(b * FO + i)) * N1 + GG + g);
        }
      }
    }
  }
}

extern "C" void kernel_launch(void* const* d_in, const int* in_sizes, int n_in,
                              void* d_out, int out_size, void* d_ws, size_t ws_size,
                              hipStream_t stream) {
  const float* region_feats = (const float*)d_in[0];
  // d_in[1] region_masks: unused by reference
  const int* rel_feats = (const int*)d_in[2];
  const float* tem_feats = (const float*)d_in[3];
  const float* rel_W = (const float*)d_in[4];
  const float* rel_b = (const float*)d_in[5];
  const float* rel_emb = (const float*)d_in[6];
  const float* tem_W = (const float*)d_in[7];
  const float* tem_b = (const float*)d_in[8];
  const float* bn_w = (const float*)d_in[9];
  const float* bn_b = (const float*)d_in[10];
  const float* bn_rm = (const float*)d_in[11];
  const float* bn_rv = (const float*)d_in[12];
  float* out = (float*)d_out;

  // Workspace layout: total 117.1 MB
  char* base = (char*)d_ws;
  u16* A1 = (u16*)base;                                   // [16640][2112] bf16 : 70,287,360
  u16* Wc = (u16*)(base + 70287360);                      // [1024][2112] bf16  :  4,325,376
  u16* A2 = (u16*)(base + 74612736);                      // [32][640][576] bf16: 23,592,960
  u16* BT = (u16*)(base + 98205696);                      // [32][512][576] bf16: 18,874,368
  float* tsum = (float*)(base + 117080064);               // [32*520] f32       :     66,560

  prep_all_kernel<<<M1 + 1024 + 5120, 256, 0, stream>>>(
      region_feats, rel_feats, rel_W, tem_W, rel_emb, tem_feats, A1, Wc, A2, tsum);
  gemm1_kernel<<<1040, 256, 0, stream>>>(A1, Wc, rel_b, tem_b,
                                         bn_w, bn_b, bn_rm, bn_rv, out, BT);
  gemm2_kernel<<<dim3(10, 8, 32), 256, 0, stream>>>(A2, BT, tsum,
                                                    bn_w, bn_b, bn_rm, bn_rv, out);
}